// Round 19
// baseline (3285.471 us; speedup 1.0000x reference)
//
#include <hip/hip_runtime.h>
#include <hip/hip_bf16.h>
#include <math.h>

#define TT 32
#define DD 64
#define NN 1024
#define VV 64
#define RR 4
#define HH 512

typedef unsigned int uint_t;
typedef unsigned short ushort_t;

__device__ __forceinline__ float sigf(float x) { return 1.0f / (1.0f + __expf(-x)); }
__device__ __forceinline__ float splus(float x) {
  return (x > 0.f) ? (x + log1pf(__expf(-x))) : log1pf(__expf(x));
}
__device__ __forceinline__ float bflo(uint_t u) { return __uint_as_float(u << 16); }
__device__ __forceinline__ float bfhi(uint_t u) { return __uint_as_float(u & 0xffff0000u); }
// RTNE pack via HW cvt (compiler emits v_cvt_pk_bf16_f32 on gfx950)
__device__ __forceinline__ uint_t packbf(float a, float b) {
  __hip_bfloat162 h2 = __float22bfloat162_rn(make_float2(a, b));
  uint_t r;
  __builtin_memcpy(&r, &h2, 4);
  return r;
}

// ============ pre-kernels (every launch; deterministic) ============
__global__ void build_gw(const float* __restrict__ W_ih, const float* __restrict__ W_hh,
                         const float* __restrict__ out_W, uint_t* __restrict__ W2g) {
  int idx = blockIdx.x * 256 + threadIdx.x;           // 2112*416
  if (idx >= 2112 * 416) return;
  int r = idx / 416, kp = idx - r * 416;
  float v[2];
  #pragma unroll
  for (int q = 0; q < 2; ++q) {
    int k = 2 * kp + q;
    float f;
    if (r < 2048) {
      int h = r >> 2, g = r & 3, row = g * 512 + h;
      f = (k < 320) ? W_ih[(size_t)row * 320 + k] : W_hh[(size_t)row * 512 + (k - 320)];
    } else {
      int j = r - 2048;
      if (k < 64) f = 0.f;
      else if (k < 320) f = out_W[(size_t)j * 768 + 512 + (k - 64)];
      else f = out_W[(size_t)j * 768 + (k - 320)];
    }
    v[q] = f;
  }
  W2g[idx] = packbf(v[0], v[1]);
}
__global__ void build_hw(const float* __restrict__ read_W, const float* __restrict__ write_W,
                         uint_t* __restrict__ W2h) {
  int idx = blockIdx.x * 256 + threadIdx.x;           // 1072*256
  if (idx >= 1072 * 256) return;
  int r = idx >> 8, kp = idx & 255;
  const float* src = (r < 280) ? (read_W + (size_t)r * 512) : (write_W + (size_t)(r - 280) * 512);
  W2h[idx] = packbf(src[2 * kp], src[2 * kp + 1]);
}
__global__ void bias_kernel(const float* __restrict__ bi, const float* __restrict__ bh,
                            float* __restrict__ o) {
  int i = blockIdx.x * 256 + threadIdx.x;
  if (i < 2048) o[i] = bi[i] + bh[i];
}
__global__ void k0_init(const float* __restrict__ x, const float* __restrict__ mem_bias,
                        const float* __restrict__ h_bias, const float* __restrict__ c_bias,
                        const float* __restrict__ read_init,
                        ushort_t* __restrict__ g_mem, uint_t* __restrict__ A2,
                        float* __restrict__ g_c, float* __restrict__ g_ws) {
  const int b = blockIdx.x, tid = threadIdx.x;
  {
    const float4* src = (const float4*)(mem_bias + (size_t)tid * VV);
    uint4* dst = (uint4*)(g_mem + (size_t)b * (NN * VV) + (size_t)tid * VV);
    #pragma unroll
    for (int p = 0; p < 8; ++p) {
      float4 va = src[2 * p], vb = src[2 * p + 1];
      uint4 o;
      o.x = packbf(va.x, va.y); o.y = packbf(va.z, va.w);
      o.z = packbf(vb.x, vb.y); o.w = packbf(vb.z, vb.w);
      dst[p] = o;
    }
  }
  if (tid < 416) {
    float v0, v1;
    if (tid < 32)      { v0 = x[((size_t)b * TT) * DD + 2 * tid]; v1 = x[((size_t)b * TT) * DD + 2 * tid + 1]; }
    else if (tid < 160){ int e = 2 * (tid - 32); v0 = read_init[e]; v1 = read_init[e + 1]; }
    else               { int e = 2 * (tid - 160); v0 = h_bias[e]; v1 = h_bias[e + 1]; }
    A2[(size_t)tid * 64 + b] = packbf(v0, v1);
  }
  if (tid < 512) g_c[(size_t)tid * 64 + b] = c_bias[tid];
  for (int i = tid; i < 8192; i += 1024) g_ws[(size_t)b * 8192 + i] = 0.f;
}

// ============ K1s: gates+out GEMM, split-K x4 (partials) ============
// blocks 0..255: gate (grp=blk>>2, kh=blk&3); blocks 256..287: out rows
__global__ __launch_bounds__(512) void k1s(
    int par, int doGate, int doOut,
    const uint_t* __restrict__ W2g, const uint_t* __restrict__ A2,
    float* __restrict__ g_gp) {
  const int blk = blockIdx.x, tid = threadIdx.x;
  const int lane = tid & 63, u = tid >> 6;
  const bool isGate = (blk < 256);
  if (isGate && !doGate) return;
  if (!isGate && !doOut) return;
  __shared__ uint_t s_tile[52 * 64];
  int kh, hglob = 0, orow = 0;
  size_t wbase;
  if (isGate) {
    int grp = blk >> 2; kh = blk & 3;
    hglob = grp * 8 + u;
    wbase = (size_t)(hglob * 4) * 416;
  } else {
    int ob = blk - 256; kh = ob & 3;
    orow = 2048 + (ob >> 2) * 8 + u;
    wbase = (size_t)orow * 416;
  }
  float acc0 = 0.f, acc1 = 0.f, acc2 = 0.f, acc3 = 0.f;
  for (int cc = 0; cc < 2; ++cc) {
    int c = kh * 2 + cc;
    for (int i = tid; i < 52 * 64; i += 512) {
      int kk = i >> 6, bb = i & 63;
      int kpg = c * 52 + kk;
      int phys = (kpg < 160) ? kpg : kpg + 256 * par;
      s_tile[i] = A2[(size_t)phys * 64 + bb];
    }
    __syncthreads();
    const uint4* w4 = (const uint4*)(W2g + wbase) + c * 13;
    if (isGate) {
      #pragma unroll
      for (int q = 0; q < 13; ++q) {
        uint4 wA = w4[q], wB = w4[104 + q], wC = w4[208 + q], wD = w4[312 + q];
        const uint_t* pA = (const uint_t*)&wA;
        const uint_t* pB = (const uint_t*)&wB;
        const uint_t* pC = (const uint_t*)&wC;
        const uint_t* pD = (const uint_t*)&wD;
        #pragma unroll
        for (int jj = 0; jj < 4; ++jj) {
          uint_t ua = s_tile[(q * 4 + jj) * 64 + lane];
          float a0 = bflo(ua), a1 = bfhi(ua);
          acc0 += bflo(pA[jj]) * a0 + bfhi(pA[jj]) * a1;
          acc1 += bflo(pB[jj]) * a0 + bfhi(pB[jj]) * a1;
          acc2 += bflo(pC[jj]) * a0 + bfhi(pC[jj]) * a1;
          acc3 += bflo(pD[jj]) * a0 + bfhi(pD[jj]) * a1;
        }
      }
    } else {
      #pragma unroll
      for (int q = 0; q < 13; ++q) {
        uint4 wA = w4[q];
        const uint_t* pA = (const uint_t*)&wA;
        #pragma unroll
        for (int jj = 0; jj < 4; ++jj) {
          uint_t ua = s_tile[(q * 4 + jj) * 64 + lane];
          acc0 += bflo(pA[jj]) * bflo(ua) + bfhi(pA[jj]) * bfhi(ua);
        }
      }
    }
    __syncthreads();
  }
  if (isGate) {
    float* d = g_gp + (size_t)kh * 135168 + (size_t)(hglob * 4) * 64 + lane;
    d[0] = acc0; d[64] = acc1; d[128] = acc2; d[192] = acc3;
  } else {
    g_gp[(size_t)kh * 135168 + (size_t)orow * 64 + lane] = acc0;
  }
}

// ============ K1c: combine(4) + LSTM + h publish + out write ============
__global__ __launch_bounds__(512) void k1c(
    int t, int par, int doGate,
    const float* __restrict__ g_gp, const float* __restrict__ gbias,
    uint_t* __restrict__ A2, float* __restrict__ g_c,
    const float* __restrict__ out_b, float* __restrict__ out) {
  const int blk = blockIdx.x, tid = threadIdx.x;
  const int lane = tid & 63, u = tid >> 6;
  if (blk < 64) {
    if (!doGate) return;
    __shared__ float s_h[512];
    const int hglob = blk * 8 + u;
    float gi = gbias[hglob], gf = gbias[512 + hglob];
    float gg = gbias[1024 + hglob], go = gbias[1536 + hglob];
    #pragma unroll
    for (int kh = 0; kh < 4; ++kh) {
      const float* p = g_gp + (size_t)kh * 135168 + (size_t)(hglob * 4) * 64 + lane;
      gi += p[0]; gf += p[64]; gg += p[128]; go += p[192];
    }
    float c0 = g_c[(size_t)hglob * 64 + lane];
    float cn = sigf(gf) * c0 + sigf(gi) * tanhf(gg);
    float hn = sigf(go) * tanhf(cn);
    g_c[(size_t)hglob * 64 + lane] = cn;
    s_h[u * 64 + lane] = hn;
    __syncthreads();
    if (tid < 256) {
      int q = tid >> 6;
      float h0 = s_h[(2 * q) * 64 + lane], h1 = s_h[(2 * q + 1) * 64 + lane];
      int kp = 160 + 256 * (par ^ 1) + blk * 4 + q;
      A2[(size_t)kp * 64 + lane] = packbf(h0, h1);
    }
  } else {
    if (t == 0) return;
    int j = (blk - 64) * 8 + u;
    float v = out_b[j];
    #pragma unroll
    for (int kh = 0; kh < 4; ++kh)
      v += g_gp[(size_t)kh * 135168 + (size_t)(2048 + j) * 64 + lane];
    out[((size_t)lane * TT + (t - 1)) * DD + j] = sigf(v);
  }
}

// ============ K2: head projections GEMM, split-K x4 ============
__global__ __launch_bounds__(512) void k2_heads(
    int wslot, const uint_t* __restrict__ W2h,
    const float* __restrict__ read_b, const float* __restrict__ write_b,
    const uint_t* __restrict__ A2, float* __restrict__ g_headp) {
  const int blk = blockIdx.x, tid = threadIdx.x;
  const int lane = tid & 63, u = tid >> 6;
  const int rgrp = blk >> 2, kh = blk & 3;
  const int r = rgrp * 8 + u;
  __shared__ uint_t s_tile[64 * 64];
  __shared__ float s_tr[8 * 65];
  const int hbase = 160 + 256 * wslot + kh * 64;
  float acc = 0.f;
  const uint_t* wrow = W2h + (size_t)r * 256 + kh * 64;
  for (int i = tid; i < 64 * 64; i += 512) {
    int kk = i >> 6, bb = i & 63;
    s_tile[i] = A2[(size_t)(hbase + kk) * 64 + bb];
  }
  __syncthreads();
  #pragma unroll 4
  for (int kk = 0; kk < 64; ++kk) {
    uint_t ua = s_tile[kk * 64 + lane];
    uint_t w = wrow[kk];
    acc += bflo(w) * bflo(ua) + bfhi(w) * bfhi(ua);
  }
  __syncthreads();
  if (kh == 0) acc += (r < 280) ? read_b[r] : write_b[r - 280];
  s_tr[u * 65 + lane] = acc;
  __syncthreads();
  if (tid < 128) {
    int bb = tid & 63, half = tid >> 6;
    float4 v;
    v.x = s_tr[(half * 4 + 0) * 65 + bb];
    v.y = s_tr[(half * 4 + 1) * 65 + bb];
    v.z = s_tr[(half * 4 + 2) * 65 + bb];
    v.w = s_tr[(half * 4 + 3) * 65 + bb];
    *(float4*)(g_headp + (size_t)kh * 69632 + (size_t)bb * 1088 + rgrp * 8 + half * 4) = v;
  }
}

// ============ K3: per-batch memory phase — mem LDS-resident ============
// Dynamic LDS: 1024 rows x 32 uints, rotation-swizzled: slot(row,c) = (c+row)&31.
// Deferred normalization: wp staged (s_part / s_wp), 1/Z folded downstream.
__global__ __launch_bounds__(1024, 4) void k3_mem(
    int t, const float* __restrict__ x, const float* __restrict__ g_headp,
    ushort_t* __restrict__ g_mem, uint_t* __restrict__ A2,
    float* __restrict__ g_ws) {
  const int b = blockIdx.x, tid = threadIdx.x;
  const int lane = tid & 63, wave = tid >> 6;
  extern __shared__ uint_t s_mem[];            // 131072 B
  __shared__ alignas(16) float s_wgA[1024];    // wgR (shift window)
  __shared__ alignas(16) float s_wgB[1024];    // wgW (shift window)
  __shared__ alignas(16) float s_part[1024];   // wpR, then einsum partials
  __shared__ alignas(16) float s_wp[1024];     // wpW
  __shared__ alignas(16) float s_reads[RR * VV];
  __shared__ alignas(16) float s_or[72];
  __shared__ alignas(16) float s_ow[200];
  __shared__ alignas(16) float s_e[VV];
  __shared__ alignas(16) float s_a[VV];
  __shared__ float s_redR[16];
  __shared__ float s_redW[16];
  uint_t* m32 = (uint_t*)(g_mem + (size_t)b * (NN * VV));
  const float* hp = g_headp + (size_t)b * 1088;

  // ---- prefetch ws history into registers ----
  float wsr[8];
  #pragma unroll
  for (int s2 = 0; s2 < 8; ++s2) wsr[s2] = g_ws[(size_t)(b * 8 + s2) * 1024 + tid];

  // ---- proj load head 0 (sum 4 split-K partials) ----
  if (tid < 70) {
    float s = 0.f;
    #pragma unroll
    for (int kh = 0; kh < 4; ++kh) s += hp[(size_t)kh * 69632 + tid];
    s_or[tid] = s;
  } else if (tid >= 128 && tid < 326) {
    int i2 = tid - 128;
    float s = 0.f;
    #pragma unroll
    for (int kh = 0; kh < 4; ++kh) s += hp[(size_t)kh * 69632 + 280 + i2];
    s_ow[i2] = s;
  }
  __syncthreads();                              // P0
  if (tid < VV) { s_e[tid] = sigf(s_ow[70 + tid]); s_a[tid] = s_ow[134 + tid]; }

  for (int hd = 0; hd < RR; ++hd) {
    // ---- dot pass over own row (tid): dual keys ----
    float dotR = 0.f, dotW = 0.f, nrm2 = 0.f;
    if (hd == 0) {
      const uint4* rowp = (const uint4*)(m32 + (size_t)tid * 32);
      const float4* orf = (const float4*)s_or;
      const float4* owf = (const float4*)s_ow;
      #pragma unroll
      for (int p = 0; p < 8; ++p) {
        uint4 m = rowp[p];
        s_mem[tid * 32 + ((4 * p + 0 + tid) & 31)] = m.x;
        s_mem[tid * 32 + ((4 * p + 1 + tid) & 31)] = m.y;
        s_mem[tid * 32 + ((4 * p + 2 + tid) & 31)] = m.z;
        s_mem[tid * 32 + ((4 * p + 3 + tid) & 31)] = m.w;
        float4 ka = orf[2 * p], kb = orf[2 * p + 1];
        float4 wa = owf[2 * p], wb = owf[2 * p + 1];
        float m0 = bflo(m.x), m1 = bfhi(m.x), m2 = bflo(m.y), m3 = bfhi(m.y);
        float m4 = bflo(m.z), m5 = bfhi(m.z), m6 = bflo(m.w), m7 = bfhi(m.w);
        nrm2 += m0 * m0 + m1 * m1 + m2 * m2 + m3 * m3 + m4 * m4 + m5 * m5 + m6 * m6 + m7 * m7;
        dotR += m0 * ka.x + m1 * ka.y + m2 * ka.z + m3 * ka.w +
                m4 * kb.x + m5 * kb.y + m6 * kb.z + m7 * kb.w;
        dotW += m0 * wa.x + m1 * wa.y + m2 * wa.z + m3 * wa.w +
                m4 * wb.x + m5 * wb.y + m6 * wb.z + m7 * wb.w;
      }
    } else {
      const float2* kr2 = (const float2*)s_or;
      const float2* kw2 = (const float2*)s_ow;
      #pragma unroll 8
      for (int c = 0; c < 32; ++c) {
        uint_t u = s_mem[tid * 32 + ((c + tid) & 31)];
        float v0 = bflo(u), v1 = bfhi(u);
        float2 kr = kr2[c], kw = kw2[c];
        nrm2 += v0 * v0 + v1 * v1;
        dotR += v0 * kr.x + v1 * kr.y;
        dotW += v0 * kw.x + v1 * kw.y;
      }
    }
    // ---- per-wave key-norm reduce ----
    float kkR, kkW;
    {
      float kR = s_or[lane]; kR *= kR;
      float kW = s_ow[lane]; kW *= kW;
      #pragma unroll
      for (int o = 32; o; o >>= 1) { kR += __shfl_xor(kR, o); kW += __shfl_xor(kW, o); }
      kkR = kR; kkW = kW;
    }
    float na = fmaxf(sqrtf(nrm2), 1e-8f);

    // ---- dual softmax chain (3 syncs, deferred normalization) ----
    float nbR = fmaxf(sqrtf(kkR), 1e-8f), nbW = fmaxf(sqrtf(kkW), 1e-8f);
    float betaR = splus(s_or[64]), betaW = splus(s_ow[64]);
    float gR = sigf(s_or[65]), gW = sigf(s_ow[65]);
    float r0 = s_or[66], r1 = s_or[67], r2 = s_or[68];
    float q0 = s_ow[66], q1 = s_ow[67], q2 = s_ow[68];
    float mxR = fmaxf(r0, fmaxf(r1, r2)), mxW = fmaxf(q0, fmaxf(q1, q2));
    float eR0 = __expf(r0 - mxR), eR1 = __expf(r1 - mxR), eR2 = __expf(r2 - mxR);
    float eW0 = __expf(q0 - mxW), eW1 = __expf(q1 - mxW), eW2 = __expf(q2 - mxW);
    float siR = 1.0f / (eR0 + eR1 + eR2), siW = 1.0f / (eW0 + eW1 + eW2);
    float gamR = 1.0f + splus(s_or[69]), gamW = 1.0f + splus(s_ow[69]);
    float eeR = __expf(betaR * dotR / (na * nbR));   // |z|<=beta: no max-sub
    float eeW = __expf(betaW * dotW / (na * nbW));
    float vR = eeR, vW = eeW;
    #pragma unroll
    for (int o = 32; o; o >>= 1) { vR += __shfl_xor(vR, o); vW += __shfl_xor(vW, o); }
    if (lane == 0) { s_redR[wave] = vR; s_redW[wave] = vW; }
    __syncthreads();                              // S1
    float SR = 0.f, SW = 0.f;
    #pragma unroll
    for (int w = 0; w < 16; ++w) { SR += s_redR[w]; SW += s_redW[w]; }
    float wgR = gR * (eeR / SR) + (1.0f - gR) * wsr[2 * hd];
    float wgW = gW * (eeW / SW) + (1.0f - gW) * wsr[2 * hd + 1];
    s_wgA[tid] = wgR;
    s_wgB[tid] = wgW;
    __syncthreads();                              // S2
    int tm = (tid + 1023) & 1023, tp = (tid + 1) & 1023;
    float wsnR = (eR0 * siR) * s_wgA[tm] + (eR1 * siR) * s_wgA[tid] + (eR2 * siR) * s_wgA[tp];
    float wsnW = (eW0 * siW) * s_wgB[tm] + (eW1 * siW) * s_wgB[tid] + (eW2 * siW) * s_wgB[tp];
    float wpR = __expf(gamR * __logf(wsnR));
    float wpW = __expf(gamW * __logf(wsnW));
    s_part[tid] = wpR;                            // unnormalized stage
    s_wp[tid] = wpW;
    vR = wpR; vW = wpW;
    #pragma unroll
    for (int o = 32; o; o >>= 1) { vR += __shfl_xor(vR, o); vW += __shfl_xor(vW, o); }
    if (lane == 0) { s_redR[wave] = vR; s_redW[wave] = vW; }
    __syncthreads();                              // S3: Z ready AND wp visible
    float ZR = 0.f, ZW = 0.f;
    #pragma unroll
    for (int w = 0; w < 16; ++w) { ZR += s_redR[w]; ZW += s_redW[w]; }
    float invZR = 1.0f / (ZR + 1e-16f);
    float invZW = 1.0f / (ZW + 1e-16f);
    float wRf = wpR * invZR;
    float wWf = wpW * invZW;
    wsr[2 * hd] = wRf;
    wsr[2 * hd + 1] = wWf;
    g_ws[(size_t)(b * 8 + 2 * hd) * 1024 + tid] = wRf;
    g_ws[(size_t)(b * 8 + 2 * hd + 1) * 1024 + tid] = wWf;

    // ---- prefetch next head's projections (hidden under einsum; s_or/ow dead) ----
    if (hd < 3) {
      if (tid < 70) {
        float s = 0.f;
        #pragma unroll
        for (int kh = 0; kh < 4; ++kh) s += hp[(size_t)kh * 69632 + (hd + 1) * 70 + tid];
        s_or[tid] = s;
      } else if (tid >= 128 && tid < 326) {
        int i2 = tid - 128;
        float s = 0.f;
        #pragma unroll
        for (int kh = 0; kh < 4; ++kh) s += hp[(size_t)kh * 69632 + 280 + (hd + 1) * 198 + i2];
        s_ow[i2] = s;
      }
    }

    // ---- fused einsum + erase in LDS (wp-scaled; head 3 erase -> EA) ----
    {
      const int cp = lane & 31, half = lane >> 5;
      const float e0 = s_e[2 * cp] * invZW, e1 = s_e[2 * cp + 1] * invZW;
      const float a0 = s_a[2 * cp] * invZW, a1 = s_a[2 * cp + 1] * invZW;
      const int rbase = wave * 64 + half;
      float acc0 = 0.f, acc1 = 0.f;
      #pragma unroll 8
      for (int q = 0; q < 32; ++q) {
        int row = rbase + 2 * q;
        int addr = row * 32 + ((cp + row) & 31);
        uint_t uu = s_mem[addr];
        float wRn = s_part[row];                  // wpR (unnormalized)
        float wWn = s_wp[row];                    // wpW (unnormalized)
        float v0 = bflo(uu), v1 = bfhi(uu);
        acc0 += wRn * v0; acc1 += wRn * v1;
        float n0 = v0 * (1.f - wWn * e0) + wWn * a0;
        float n1 = v1 * (1.f - wWn * e1) + wWn * a1;
        uint_t nu = packbf(n0, n1);
        if (hd < 3) s_mem[addr] = nu;
        else        m32[(size_t)row * 32 + cp] = nu;   // final mem -> EA, coalesced
      }
      acc0 += __shfl_xor(acc0, 32);
      acc1 += __shfl_xor(acc1, 32);
      if (half == 0) *(float2*)(s_part + wave * 64 + 2 * cp) = make_float2(acc0, acc1);
    }
    __syncthreads();                              // S5
    if (tid < VV) {
      float s = 0.f;
      #pragma unroll
      for (int w2 = 0; w2 < 16; ++w2) s += s_part[w2 * 64 + tid];
      s_reads[hd * VV + tid] = s * invZR;
      if (hd < 3) { s_e[tid] = sigf(s_ow[70 + tid]); s_a[tid] = s_ow[134 + tid]; }
    }
  } // hd
  __syncthreads();

  // publish reads_t and x_{t+1} into A (bf16 pairs)
  if (tid < 128)
    A2[(size_t)(32 + tid) * 64 + b] = packbf(s_reads[2 * tid], s_reads[2 * tid + 1]);
  if (tid < 32 && t + 1 < TT) {
    float v0 = x[((size_t)b * TT + t + 1) * DD + 2 * tid];
    float v1 = x[((size_t)b * TT + t + 1) * DD + 2 * tid + 1];
    A2[(size_t)tid * 64 + b] = packbf(v0, v1);
  }
}

extern "C" void kernel_launch(void* const* d_in, const int* in_sizes, int n_in,
                              void* d_out, int out_size, void* d_ws, size_t ws_size,
                              hipStream_t stream) {
  char* ws = (char*)d_ws;
  ushort_t* g_mem = (ushort_t*)ws;                 //  8,388,608
  uint_t* g_A2    = (uint_t*)(ws + 8388608);       //    172,032
  float* g_c      = (float*)(ws + 8560640);        //    131,072
  float* g_ws     = (float*)(ws + 8691712);        //  2,097,152
  float* g_headp  = (float*)(ws + 10788864);       //  1,114,112 (4 halves)
  uint_t* W2g     = (uint_t*)(ws + 11902976);      //  3,514,368
  uint_t* W2h     = (uint_t*)(ws + 15417344);      //  1,097,728
  float* gbias    = (float*)(ws + 16515072);       //      8,192
  float* g_gp     = (float*)(ws + 16523264);       //  2,162,688  (~18.7 MB)

  const float* x        = (const float*)d_in[0];
  const float* mem_bias = (const float*)d_in[1];
  const float* h_bias   = (const float*)d_in[2];
  const float* c_bias   = (const float*)d_in[3];
  const float* W_ih     = (const float*)d_in[4];
  const float* W_hh     = (const float*)d_in[5];
  const float* b_ih     = (const float*)d_in[6];
  const float* b_hh     = (const float*)d_in[7];
  const float* read_W   = (const float*)d_in[8];
  const float* read_b   = (const float*)d_in[9];
  const float* write_W  = (const float*)d_in[10];
  const float* write_b  = (const float*)d_in[11];
  const float* read_init= (const float*)d_in[12];
  const float* out_W    = (const float*)d_in[13];
  const float* out_b    = (const float*)d_in[14];
  float* out = (float*)d_out;

  bias_kernel<<<8, 256, 0, stream>>>(b_ih, b_hh, gbias);
  build_gw<<<3432, 256, 0, stream>>>(W_ih, W_hh, out_W, W2g);
  build_hw<<<1072, 256, 0, stream>>>(read_W, write_W, W2h);
  k0_init<<<64, 1024, 0, stream>>>(x, mem_bias, h_bias, c_bias, read_init,
                                   g_mem, g_A2, g_c, g_ws);
  for (int t = 0; t < TT; ++t) {
    k1s<<<288, 512, 0, stream>>>(t & 1, 1, (t > 0) ? 1 : 0, W2g, g_A2, g_gp);
    k1c<<<72, 512, 0, stream>>>(t, t & 1, 1, g_gp, gbias, g_A2, g_c, out_b, out);
    k2_heads<<<536, 512, 0, stream>>>((t + 1) & 1, W2h, read_b, write_b, g_A2, g_headp);
    k3_mem<<<64, 1024, 131072, stream>>>(t, x, g_headp, g_mem, g_A2, g_ws);
  }
  // final out(t=31): out partials from h_31 (slot 0) + reads_31, then combine
  k1s<<<288, 512, 0, stream>>>(0, 0, 1, W2g, g_A2, g_gp);
  k1c<<<72, 512, 0, stream>>>(TT, 0, 0, g_gp, gbias, g_A2, g_c, out_b, out);
}